// Round 4
// baseline (107.963 us; speedup 1.0000x reference)
//
#include <hip/hip_runtime.h>
#include <hip/hip_bf16.h>
#include <math.h>

#define NSEQ 4096
#define TN 288
#define EPSF 1e-5f

typedef short bf16x8 __attribute__((ext_vector_type(8)));
typedef float f32x4 __attribute__((ext_vector_type(4)));
typedef unsigned int u32x4 __attribute__((ext_vector_type(4)));

// ---- d_ws layout (shorts): preconverted bf16 weights ----
#define WSV 0        // Wv 16x16
#define WSK 256      // Wk 16x16
#define WSQ 512      // Wq 16x16
#define WSO 768      // Wo 64x64 row-major
#define WS1 4864     // W1 256x64 row-major
#define WS2 21248    // W2 64x256 row-major

// ---- LDS pool: 27136 bytes -> 6 blocks/CU (6*27136 = 159.0 KB <= 160 KB) ----
// short-index constants; byte ranges in comments:
#define QP_S   0      // qp  [48][72]  [0,6912)       P1->P2 (per-head cols)
#define KP_S   3456   // kp  [48][72]  [6912,13824)   P1->P2; o overlays (per-head cols)
#define VPT_S  6912   // vpT [64][48]  [13824,19968)  P1->P3 (per-head rows)
#define ATT_S  9984   // att 4x[16][56][19968,27136)  per-head 896 shorts, per-qblock reuse
#define OUT2_F 3456   // out2 f32[48][64] [13824,26112) P4->LN1 (over vpT/att)
#define XBF_S  0      // xbf [48][72]  [0,6912)       LN1->FF1 + LN2 residual
#define H_S    3456   // h   [48][136] [6912,19968)   FF1->FF2 (per 128-half)
#define FFO_S  9984   // ffo [48][72]  [19968,26880)  FF2->LN2

__device__ __forceinline__ unsigned short f2bf_u(float f) {
    __hip_bfloat16 h = __float2bfloat16(f);
    return *reinterpret_cast<const unsigned short*>(&h);
}
__device__ __forceinline__ unsigned int pk2(float a, float b) {
    return (unsigned int)f2bf_u(a) | ((unsigned int)f2bf_u(b) << 16);
}
__device__ __forceinline__ float bits2f(unsigned int u) { return __uint_as_float(u); }
__device__ __forceinline__ bf16x8 mk8(float4 a, float4 b) {
    u32x4 u;
    u.x = pk2(a.x, a.y); u.y = pk2(a.z, a.w);
    u.z = pk2(b.x, b.y); u.w = pk2(b.z, b.w);
    return __builtin_bit_cast(bf16x8, u);
}
__device__ __forceinline__ float halfsum(float v) {   // sum over 32-lane half
    v += __shfl_xor(v, 1);
    v += __shfl_xor(v, 2);
    v += __shfl_xor(v, 4);
    v += __shfl_xor(v, 8);
    v += __shfl_xor(v, 16);
    return v;
}

// ---------- prologue: f32 -> bf16 weight conversion into d_ws ----------
__global__ void wconv_kernel(const float* __restrict__ Wv, const float* __restrict__ Wk,
                             const float* __restrict__ Wq, const float* __restrict__ Wo,
                             const float* __restrict__ W1, const float* __restrict__ W2,
                             short* __restrict__ ws) {
    int i = blockIdx.x * 256 + threadIdx.x;   // 0..37631
    float v;
    if (i < 256)        v = Wv[i];
    else if (i < 512)   v = Wk[i - 256];
    else if (i < 768)   v = Wq[i - 512];
    else if (i < 4864)  v = Wo[i - 768];
    else if (i < 21248) v = W1[i - 4864];
    else                v = W2[i - 21248];
    ws[i] = (short)f2bf_u(v);
}

__global__ __launch_bounds__(256, 8)
void ttrans_kernel(const float* __restrict__ value,
                   const float* __restrict__ keys,
                   const float* __restrict__ query,
                   const float* __restrict__ bo,
                   const float* __restrict__ temb,
                   const float* __restrict__ ln1g,
                   const float* __restrict__ ln1b,
                   const float* __restrict__ ln2g,
                   const float* __restrict__ ln2b,
                   const float* __restrict__ pb1,
                   const float* __restrict__ pb2,
                   const short* __restrict__ ws,
                   const int* __restrict__ tqp,
                   float* __restrict__ out)
{
    __shared__ __align__(16) unsigned char smem[27136];
    short* S16 = reinterpret_cast<short*>(smem);
    float* S32 = reinterpret_cast<float*>(smem);

    const int tid  = threadIdx.x;
    const int lane = tid & 63;
    const int w    = tid >> 6;           // wave 0..3 (= head in P1-P3)
    const int l15  = lane & 15;
    const int lg   = lane >> 4;
    const int n    = blockIdx.x;
    const size_t gbase = (size_t)n * 3072;
    const int tqv  = *tqp;
    const int c0   = (lane & 31) * 2;    // pair-col for LN phases
    const int sub  = lane >> 5;
    const int hh   = w;

    // ================= P1: per-head projections, A-frags direct from global
    {
        bf16x8 bWv = {}, bWk = {}, bWq = {};
        if (lane < 32) {
            bWv = *reinterpret_cast<const bf16x8*>(&ws[WSV + l15 * 16 + lg * 8]);
            bWk = *reinterpret_cast<const bf16x8*>(&ws[WSK + l15 * 16 + lg * 8]);
            bWq = *reinterpret_cast<const bf16x8*>(&ws[WSQ + l15 * 16 + lg * 8]);
        }
        #pragma unroll
        for (int rt = 0; rt < 3; ++rt) {
            float4 q0 = {0,0,0,0}, q1 = {0,0,0,0};
            float4 k0 = {0,0,0,0}, k1 = {0,0,0,0};
            float4 v0 = {0,0,0,0}, v1 = {0,0,0,0};
            if (lane < 32) {
                int t = rt * 16 + l15;
                int ti = ((tqv % TN) + TN + t) % TN;
                const int off = t * 64 + hh * 16 + lg * 8;
                q0 = *reinterpret_cast<const float4*>(&query[gbase + off]);
                q1 = *reinterpret_cast<const float4*>(&query[gbase + off + 4]);
                k0 = *reinterpret_cast<const float4*>(&keys [gbase + off]);
                k1 = *reinterpret_cast<const float4*>(&keys [gbase + off + 4]);
                v0 = *reinterpret_cast<const float4*>(&value[gbase + off]);
                v1 = *reinterpret_cast<const float4*>(&value[gbase + off + 4]);
                const int toff = ti * 64 + hh * 16 + lg * 8;
                float4 t0 = *reinterpret_cast<const float4*>(&temb[toff]);
                float4 t1 = *reinterpret_cast<const float4*>(&temb[toff + 4]);
                q0.x += t0.x; q0.y += t0.y; q0.z += t0.z; q0.w += t0.w;
                q1.x += t1.x; q1.y += t1.y; q1.z += t1.z; q1.w += t1.w;
                k0.x += t0.x; k0.y += t0.y; k0.z += t0.z; k0.w += t0.w;
                k1.x += t1.x; k1.y += t1.y; k1.z += t1.z; k1.w += t1.w;
            }
            bf16x8 aQ = mk8(q0, q1), aK = mk8(k0, k1), aV = mk8(v0, v1);
            f32x4 z = {0.f,0.f,0.f,0.f};
            f32x4 cQ = __builtin_amdgcn_mfma_f32_16x16x32_bf16(aQ, bWq, z, 0, 0, 0);
            f32x4 cK = __builtin_amdgcn_mfma_f32_16x16x32_bf16(aK, bWk, z, 0, 0, 0);
            f32x4 cV = __builtin_amdgcn_mfma_f32_16x16x32_bf16(aV, bWv, z, 0, 0, 0);
            #pragma unroll
            for (int r = 0; r < 4; ++r) {
                int row = rt * 16 + lg * 4 + r;
                S16[QP_S + row * 72 + hh * 16 + l15] = (short)f2bf_u(cQ[r]);
                S16[KP_S + row * 72 + hh * 16 + l15] = (short)f2bf_u(cK[r]);
                S16[VPT_S + (hh * 16 + l15) * 48 + row] = (short)f2bf_u(cV[r]);
            }
        }
    }
    // no barrier: P2/P3 consume only this wave's per-head regions

    // ================= P2+P3 fused per 16-query block (wave w = head w)
    {
        bf16x8 bK0 = {}, bK1 = {}, bK2 = {};
        if (lane < 32) {
            bK0 = *reinterpret_cast<const bf16x8*>(&S16[KP_S + ( 0 + l15) * 72 + hh * 16 + lg * 8]);
            bK1 = *reinterpret_cast<const bf16x8*>(&S16[KP_S + (16 + l15) * 72 + hh * 16 + lg * 8]);
            bK2 = *reinterpret_cast<const bf16x8*>(&S16[KP_S + (32 + l15) * 72 + hh * 16 + lg * 8]);
        }
        bf16x8 vA = *reinterpret_cast<const bf16x8*>(&S16[VPT_S + (hh * 16 + l15) * 48 + lg * 8]);
        bf16x8 vB = {};
        if (lane < 32)
            vB = *reinterpret_cast<const bf16x8*>(&S16[VPT_S + (hh * 16 + l15) * 48 + 32 + lg * 8]);

        #pragma unroll
        for (int rt = 0; rt < 3; ++rt) {
            bf16x8 aQ = {};
            if (lane < 32)
                aQ = *reinterpret_cast<const bf16x8*>(&S16[QP_S + (rt * 16 + l15) * 72 + hh * 16 + lg * 8]);
            f32x4 z = {0.f,0.f,0.f,0.f};
            f32x4 e0 = __builtin_amdgcn_mfma_f32_16x16x32_bf16(aQ, bK0, z, 0, 0, 0);
            f32x4 e1 = __builtin_amdgcn_mfma_f32_16x16x32_bf16(aQ, bK1, z, 0, 0, 0);
            f32x4 e2 = __builtin_amdgcn_mfma_f32_16x16x32_bf16(aQ, bK2, z, 0, 0, 0);
            #pragma unroll
            for (int r = 0; r < 4; ++r) {
                int t = rt * 16 + lg * 4 + r;   // global query index
                float v0 = ( 0 + l15 <= t) ? e0[r] : -1e6f;
                float v1 = (16 + l15 <= t) ? e1[r] : -1e6f;
                float v2 = (32 + l15 <= t) ? e2[r] : -1e6f;
                v0 = fminf(5.f, fmaxf(-5.f, v0 * 0.125f));
                v1 = fminf(5.f, fmaxf(-5.f, v1 * 0.125f));
                v2 = fminf(5.f, fmaxf(-5.f, v2 * 0.125f));
                float m = fmaxf(v0, fmaxf(v1, v2));
                m = fmaxf(m, __shfl_xor(m, 1));
                m = fmaxf(m, __shfl_xor(m, 2));
                m = fmaxf(m, __shfl_xor(m, 4));
                m = fmaxf(m, __shfl_xor(m, 8));
                float p0 = __expf(v0 - m), p1 = __expf(v1 - m), p2 = __expf(v2 - m);
                float s = p0 + p1 + p2;
                s += __shfl_xor(s, 1);
                s += __shfl_xor(s, 2);
                s += __shfl_xor(s, 4);
                s += __shfl_xor(s, 8);
                float inv = 1.f / s;
                int tl = lg * 4 + r;            // row within qblock
                S16[ATT_S + hh * 896 + tl * 56 +  0 + l15] = (short)f2bf_u(p0 * inv);
                S16[ATT_S + hh * 896 + tl * 56 + 16 + l15] = (short)f2bf_u(p1 * inv);
                S16[ATT_S + hh * 896 + tl * 56 + 32 + l15] = (short)f2bf_u(p2 * inv);
            }
            // PV for this qblock (same-wave in-order DS: writes above precede reads)
            bf16x8 a0 = *reinterpret_cast<const bf16x8*>(&S16[ATT_S + hh * 896 + l15 * 56 + lg * 8]);
            bf16x8 a1 = {};
            if (lane < 32)
                a1 = *reinterpret_cast<const bf16x8*>(&S16[ATT_S + hh * 896 + l15 * 56 + 32 + lg * 8]);
            f32x4 oc = __builtin_amdgcn_mfma_f32_16x16x32_bf16(a0, vA, z, 0, 0, 0);
            oc = __builtin_amdgcn_mfma_f32_16x16x32_bf16(a1, vB, oc, 0, 0, 0);
            #pragma unroll
            for (int r = 0; r < 4; ++r)
                S16[KP_S + (rt * 16 + lg * 4 + r) * 72 + hh * 16 + l15] = (short)f2bf_u(oc[r]);
        }
    }
    __syncthreads();   // (1) P4 reads all heads' o columns

    // ================= P4: out2 = o @ Wo^T  (wave w owns output cols w*16..+15)
    {
        bf16x8 bO0 = *reinterpret_cast<const bf16x8*>(&ws[WSO + (w * 16 + l15) * 64 + lg * 8]);
        bf16x8 bO1 = *reinterpret_cast<const bf16x8*>(&ws[WSO + (w * 16 + l15) * 64 + 32 + lg * 8]);
        #pragma unroll
        for (int mt = 0; mt < 3; ++mt) {
            bf16x8 a0 = *reinterpret_cast<const bf16x8*>(&S16[KP_S + (mt * 16 + l15) * 72 + lg * 8]);
            bf16x8 a1 = *reinterpret_cast<const bf16x8*>(&S16[KP_S + (mt * 16 + l15) * 72 + 32 + lg * 8]);
            f32x4 c = {0.f,0.f,0.f,0.f};
            c = __builtin_amdgcn_mfma_f32_16x16x32_bf16(a0, bO0, c, 0, 0, 0);
            c = __builtin_amdgcn_mfma_f32_16x16x32_bf16(a1, bO1, c, 0, 0, 0);
            #pragma unroll
            for (int r = 0; r < 4; ++r)
                S32[OUT2_F + (mt * 16 + lg * 4 + r) * 64 + w * 16 + l15] = c[r];
        }
    }
    __syncthreads();   // (2)

    // ================= LN1: wave-per-row-pair; q residual re-read from global
    {
        float2 bo2  = *reinterpret_cast<const float2*>(&bo[c0]);
        float2 g12  = *reinterpret_cast<const float2*>(&ln1g[c0]);
        float2 be12 = *reinterpret_cast<const float2*>(&ln1b[c0]);
        #pragma unroll
        for (int it2 = 0; it2 < 6; ++it2) {
            int t = w * 12 + it2 * 2 + sub;
            int ti = ((tqv % TN) + TN + t) % TN;
            float2 o2 = *reinterpret_cast<const float2*>(&S32[OUT2_F + t * 64 + c0]);
            float2 q2 = *reinterpret_cast<const float2*>(&query[gbase + t * 64 + c0]);
            float2 t2 = *reinterpret_cast<const float2*>(&temb[ti * 64 + c0]);
            float v0 = o2.x + bo2.x + q2.x + t2.x;
            float v1 = o2.y + bo2.y + q2.y + t2.y;
            float mu = halfsum(v0 + v1) * (1.f / 64.f);
            float d0 = v0 - mu, d1 = v1 - mu;
            float var = halfsum(d0 * d0 + d1 * d1) * (1.f / 64.f);
            float rs = rsqrtf(var + EPSF);
            float x0 = d0 * rs * g12.x + be12.x;
            float x1 = d1 * rs * g12.y + be12.y;
            *reinterpret_cast<unsigned int*>(&S16[XBF_S + t * 72 + c0]) = pk2(x0, x1);
        }
    }
    __syncthreads();   // (3)

    // ================= FF in two 128-wide halves, f32 accum across halves
    f32x4 ffC[3];
    #pragma unroll
    for (int mt = 0; mt < 3; ++mt) ffC[mt] = (f32x4){0.f,0.f,0.f,0.f};

    #pragma unroll
    for (int hb = 0; hb < 2; ++hb) {
        // FF1: wave w handles local j16 in {2w, 2w+1}
        #pragma unroll
        for (int jj = 0; jj < 2; ++jj) {
            int j16 = w * 2 + jj;             // 0..7 within half
            int jrow = (hb * 8 + j16) * 16 + l15;
            bf16x8 b0 = *reinterpret_cast<const bf16x8*>(&ws[WS1 + jrow * 64 + lg * 8]);
            bf16x8 b1 = *reinterpret_cast<const bf16x8*>(&ws[WS1 + jrow * 64 + 32 + lg * 8]);
            float b1v = pb1[jrow];
            #pragma unroll
            for (int mt = 0; mt < 3; ++mt) {
                bf16x8 a0 = *reinterpret_cast<const bf16x8*>(&S16[XBF_S + (mt * 16 + l15) * 72 + lg * 8]);
                bf16x8 a1 = *reinterpret_cast<const bf16x8*>(&S16[XBF_S + (mt * 16 + l15) * 72 + 32 + lg * 8]);
                f32x4 c = {0.f,0.f,0.f,0.f};
                c = __builtin_amdgcn_mfma_f32_16x16x32_bf16(a0, b0, c, 0, 0, 0);
                c = __builtin_amdgcn_mfma_f32_16x16x32_bf16(a1, b1, c, 0, 0, 0);
                #pragma unroll
                for (int r = 0; r < 4; ++r)
                    S16[H_S + (mt * 16 + lg * 4 + r) * 136 + j16 * 16 + l15] =
                        (short)f2bf_u(fmaxf(c[r] + b1v, 0.f));
            }
        }
        __syncthreads();   // (4)/(6)

        // FF2: accumulate this half's contribution
        {
            bf16x8 bw0 = *reinterpret_cast<const bf16x8*>(&ws[WS2 + (w * 16 + l15) * 256 + hb * 128 +  0 + lg * 8]);
            bf16x8 bw1 = *reinterpret_cast<const bf16x8*>(&ws[WS2 + (w * 16 + l15) * 256 + hb * 128 + 32 + lg * 8]);
            bf16x8 bw2 = *reinterpret_cast<const bf16x8*>(&ws[WS2 + (w * 16 + l15) * 256 + hb * 128 + 64 + lg * 8]);
            bf16x8 bw3 = *reinterpret_cast<const bf16x8*>(&ws[WS2 + (w * 16 + l15) * 256 + hb * 128 + 96 + lg * 8]);
            #pragma unroll
            for (int mt = 0; mt < 3; ++mt) {
                bf16x8 a0 = *reinterpret_cast<const bf16x8*>(&S16[H_S + (mt * 16 + l15) * 136 +  0 + lg * 8]);
                bf16x8 a1 = *reinterpret_cast<const bf16x8*>(&S16[H_S + (mt * 16 + l15) * 136 + 32 + lg * 8]);
                bf16x8 a2 = *reinterpret_cast<const bf16x8*>(&S16[H_S + (mt * 16 + l15) * 136 + 64 + lg * 8]);
                bf16x8 a3 = *reinterpret_cast<const bf16x8*>(&S16[H_S + (mt * 16 + l15) * 136 + 96 + lg * 8]);
                ffC[mt] = __builtin_amdgcn_mfma_f32_16x16x32_bf16(a0, bw0, ffC[mt], 0, 0, 0);
                ffC[mt] = __builtin_amdgcn_mfma_f32_16x16x32_bf16(a1, bw1, ffC[mt], 0, 0, 0);
                ffC[mt] = __builtin_amdgcn_mfma_f32_16x16x32_bf16(a2, bw2, ffC[mt], 0, 0, 0);
                ffC[mt] = __builtin_amdgcn_mfma_f32_16x16x32_bf16(a3, bw3, ffC[mt], 0, 0, 0);
            }
        }
        __syncthreads();   // (5)/(7a) — protects h before rewrite / before ffo consumers
    }

    // bias + store ffo
    {
        float b2v = pb2[w * 16 + l15];
        #pragma unroll
        for (int mt = 0; mt < 3; ++mt)
            #pragma unroll
            for (int r = 0; r < 4; ++r)
                S16[FFO_S + (mt * 16 + lg * 4 + r) * 72 + w * 16 + l15] =
                    (short)f2bf_u(ffC[mt][r] + b2v);
    }
    __syncthreads();   // (7)

    // ================= LN2 + store
    {
        float2 g22  = *reinterpret_cast<const float2*>(&ln2g[c0]);
        float2 be22 = *reinterpret_cast<const float2*>(&ln2b[c0]);
        #pragma unroll
        for (int it2 = 0; it2 < 6; ++it2) {
            int t = w * 12 + it2 * 2 + sub;
            unsigned int fp = *reinterpret_cast<const unsigned int*>(&S16[FFO_S + t * 72 + c0]);
            unsigned int xp = *reinterpret_cast<const unsigned int*>(&S16[XBF_S + t * 72 + c0]);
            float v0 = bits2f(fp << 16) + bits2f(xp << 16);
            float v1 = bits2f(fp & 0xffff0000u) + bits2f(xp & 0xffff0000u);
            float mu = halfsum(v0 + v1) * (1.f / 64.f);
            float d0 = v0 - mu, d1 = v1 - mu;
            float var = halfsum(d0 * d0 + d1 * d1) * (1.f / 64.f);
            float rs = rsqrtf(var + EPSF);
            float y0 = d0 * rs * g22.x + be22.x;
            float y1 = d1 * rs * g22.y + be22.y;
            *reinterpret_cast<float2*>(&out[gbase + t * 64 + c0]) = make_float2(y0, y1);
        }
    }
}

extern "C" void kernel_launch(void* const* d_in, const int* in_sizes, int n_in,
                              void* d_out, int out_size, void* d_ws, size_t ws_size,
                              hipStream_t stream) {
    const float* value = (const float*)d_in[0];
    const float* keys  = (const float*)d_in[1];
    const float* query = (const float*)d_in[2];
    const float* Wv    = (const float*)d_in[3];
    const float* Wk    = (const float*)d_in[4];
    const float* Wq    = (const float*)d_in[5];
    const float* Wo    = (const float*)d_in[6];
    const float* bo    = (const float*)d_in[7];
    const float* temb  = (const float*)d_in[8];
    const float* ln1g  = (const float*)d_in[9];
    const float* ln1b  = (const float*)d_in[10];
    const float* ln2g  = (const float*)d_in[11];
    const float* ln2b  = (const float*)d_in[12];
    const float* W1    = (const float*)d_in[13];
    const float* b1    = (const float*)d_in[14];
    const float* W2    = (const float*)d_in[15];
    const float* b2    = (const float*)d_in[16];
    const int*   tq    = (const int*)d_in[17];
    float* outp = (float*)d_out;
    short* ws = (short*)d_ws;

    hipLaunchKernelGGL(wconv_kernel, dim3(147), dim3(256), 0, stream,
                       Wv, Wk, Wq, Wo, W1, W2, ws);
    hipLaunchKernelGGL(ttrans_kernel, dim3(NSEQ), dim3(256), 0, stream,
                       value, keys, query, bo, temb,
                       ln1g, ln1b, ln2g, ln2b, b1, b2, ws, tq, outp);
}